// Round 12
// baseline (695.297 us; speedup 1.0000x reference)
//
#include <hip/hip_runtime.h>
#include <hip/hip_bf16.h>
#include <math.h>

#define B_SZ   32
#define NXX    16384
#define IN_DIM 3
#define DIM    64
#define JM     16
#define MODE   128
#define RANKK  4
#define FC_DIM 128
#define N_LAY  3

typedef __attribute__((ext_vector_type(8))) short bf16x8;
typedef __attribute__((ext_vector_type(4))) float f32x4;
typedef unsigned short u16;

// Fast gelu: v * sigmoid(2u), u = sqrt(2/pi)*(v + 0.044715 v^3).
__device__ __forceinline__ float gelu_fast(float v) {
    float p = v * (0.7978845608f + 0.0356774081f * v * v);
    float e = __expf(-2.f * p);
    return v * __builtin_amdgcn_rcpf(1.f + e);
}
__device__ __forceinline__ u16 to_bf16(float v) {
    __hip_bfloat16 b = __float2bfloat16(v);
    return *(u16*)&b;
}

// ---------------------------------------------------------------------------
__global__ __launch_bounds__(256) void k_zero(float* __restrict__ p, int n) {
    int i = blockIdx.x * 256 + threadIdx.x;
    if (i < n) p[i] = 0.f;
}

// H[j,k,l] bf16 row-major (l contig = A-frag-ready for m=k, kk=l).
__global__ __launch_bounds__(256) void k_build_H(
        const float* __restrict__ Dout, const float* __restrict__ Din,
        const float* __restrict__ product, const float* __restrict__ A,
        const float* __restrict__ Bm, u16* __restrict__ Hbf) {
    int idx = blockIdx.x * 256 + threadIdx.x;
    int j = idx >> 14;
    int k = (idx >> 7) & 127;
    int l = idx & 127;
    float v = Dout[j * MODE + k] * Din[j * MODE + l] * product[k * MODE + l];
#pragma unroll
    for (int r = 0; r < RANKK; ++r)
        v += A[(j * RANKK + r) * MODE + k] * Bm[(j * RANKK + r) * MODE + l];
    Hbf[idx] = to_bf16(v);
}

// WsT[lay][j][o][i] = Wsp[lay][i][o][j] bf16 (i contig).  grid 768 x 256.
__global__ __launch_bounds__(256) void k_setup_wst(
        const float* __restrict__ Wsp, u16* __restrict__ WsT) {
    int idx = blockIdx.x * 256 + threadIdx.x;   // ((lay*16+j)*64+o)*64+i
    int i = idx & 63, o = (idx >> 6) & 63, j = (idx >> 12) & 15, lay = idx >> 16;
    WsT[idx] = to_bf16(Wsp[(((size_t)lay * 64 + i) * 64 + o) * 16 + j]);
}

// bases (fp32 [x][k]) -> FRAG-MAJOR single bf16 plane.  grid 8192 x 256.
__global__ __launch_bounds__(256) void k_setup_bases(
        const float* __restrict__ bases, u16* __restrict__ bh) {
    int idx = blockIdx.x * 256 + threadIdx.x;
    int x = idx >> 7, k = idx & 127;
    size_t off = (size_t)(k >> 3) * 131072 + (size_t)x * 8 + (k & 7);
    bh[off] = to_bf16(bases[idx]);
}

// wbT[l][x] = wbases[x][l], single bf16 plane.  grid (512, 4) x 256, LDS-tiled.
__global__ __launch_bounds__(256) void k_setup_wbT(
        const float* __restrict__ wb, u16* __restrict__ Th) {
    __shared__ float tile[32][33];
    int bx = blockIdx.x, bl = blockIdx.y;
    int t = threadIdx.x;
    int i = t >> 5, jj = t & 31;
#pragma unroll
    for (int r = 0; r < 4; ++r)
        tile[i + r * 8][jj] = wb[(size_t)(bx * 32 + i + r * 8) * MODE + bl * 32 + jj];
    __syncthreads();
#pragma unroll
    for (int r = 0; r < 4; ++r) {
        int l = bl * 32 + i + r * 8;
        int x = bx * 32 + jj;
        Th[(size_t)l * NXX + x] = to_bf16(tile[jj][i + r * 8]);
    }
}

// W1T[f*64+c] = W1[c*128+f] single bf16 plane.  grid 32 x 256
__global__ __launch_bounds__(256) void k_setup_w1t(
        const float* __restrict__ W1, u16* __restrict__ wh) {
    int i = blockIdx.x * 256 + threadIdx.x;
    int f = i >> 6, c = i & 63;
    wh[i] = to_bf16(W1[c * FC_DIM + f]);
}

// fc0: h[b,x,c] (single bf16 plane), coalesced ushort8 stores.
// grid (512, 32) x 256.
__global__ __launch_bounds__(256) void k_fc0(
        const float* __restrict__ x, const float* __restrict__ W0,
        const float* __restrict__ b0, u16* __restrict__ hh) {
    __shared__ float w0s[IN_DIM * DIM + DIM];
    int t = threadIdx.x;
    if (t < IN_DIM * DIM) w0s[t] = W0[t];
    if (t < DIM) w0s[IN_DIM * DIM + t] = b0[t];
    __syncthreads();
    int b = blockIdx.y;
    int xi = blockIdx.x * 32 + (t >> 3);
    int c8 = (t & 7) * 8;
    const float* xp = x + ((size_t)b * NXX + xi) * IN_DIM;
    float x0 = xp[0], x1 = xp[1], x2 = xp[2];
    u16 rh[8];
#pragma unroll
    for (int i = 0; i < 8; ++i) {
        int c = c8 + i;
        float v = x0 * w0s[c] + x1 * w0s[DIM + c] + x2 * w0s[2 * DIM + c]
                + w0s[3 * DIM + c];
        rh[i] = to_bf16(v);
    }
    size_t o = ((size_t)(b << 14) + xi) * 64 + c8;
    *(ushort4*)(hh + o)     = make_ushort4(rh[0], rh[1], rh[2], rh[3]);
    *(ushort4*)(hh + o + 4) = make_ushort4(rh[4], rh[5], rh[6], rh[7]);
}

// ---------------------------------------------------------------------------
// Spectral via MFMA: xh[b][c][l] += sum_x h[b][x][c] * wbases[x][l]
// PING-PONG LDS: one barrier/iter; tile it+1 global loads overlap tile it MFMA.
// grid (32 b, 32 ks) x 256 (4 waves; wave = 16c x 32l), 512-x slab per block.
#define SPAD 72
__global__ __launch_bounds__(256) void k_spectral_mfma(
        const u16* __restrict__ Hh,
        const u16* __restrict__ Wh,
        float* __restrict__ xh) {
    __shared__ u16 Ash[2][64 * SPAD];
    int t = threadIdx.x;
    int wave = t >> 6, lane = t & 63, quad = lane >> 4, l16 = lane & 15;
    int b = blockIdx.x;
    int x0 = blockIdx.y * 512;
    int cq = (t & 15) * 4;
    int xq = (t >> 4) * 4;
    int colw = (xq + ((t & 7) << 3)) & 63;
    const u16* srch = Hh + ((size_t)(b << 14) + x0 + xq) * 64 + cq;
    int l0 = wave * 32;
    const u16* w0h = Wh + (size_t)(l0 + l16) * NXX + x0;
    const u16* w1h = Wh + (size_t)(l0 + 16 + l16) * NXX + x0;
    f32x4 acc[4][2] = {};
    ushort4 r0, r1, r2, r3;
    // prologue: tile 0 -> regs -> Ash[0]
    r0 = *(const ushort4*)(srch);
    r1 = *(const ushort4*)(srch + 64);
    r2 = *(const ushort4*)(srch + 128);
    r3 = *(const ushort4*)(srch + 192);
    {
        u16* A = Ash[0];
        *(ushort4*)&A[(cq + 0) * SPAD + colw] = make_ushort4(r0.x, r1.x, r2.x, r3.x);
        *(ushort4*)&A[(cq + 1) * SPAD + colw] = make_ushort4(r0.y, r1.y, r2.y, r3.y);
        *(ushort4*)&A[(cq + 2) * SPAD + colw] = make_ushort4(r0.z, r1.z, r2.z, r3.z);
        *(ushort4*)&A[(cq + 3) * SPAD + colw] = make_ushort4(r0.w, r1.w, r2.w, r3.w);
    }
    for (int it = 0; it < 8; ++it) {
        __syncthreads();                      // Ash[it&1] ready
        int cur = it & 1;
        if (it < 7) {                         // prefetch tile it+1 (overlaps MFMA)
            const u16* s = srch + (size_t)(it + 1) * 4096;
            r0 = *(const ushort4*)(s);
            r1 = *(const ushort4*)(s + 64);
            r2 = *(const ushort4*)(s + 128);
            r3 = *(const ushort4*)(s + 192);
        }
        const u16* A = Ash[cur];
#pragma unroll
        for (int k0 = 0; k0 < 64; k0 += 32) {
            bf16x8 afh[4];
#pragma unroll
            for (int ct = 0; ct < 4; ++ct) {
                int rr = ct * 16 + l16;
                int ro = rr * SPAD + (((k0 + quad * 8) + (((rr >> 2) & 7) << 3)) & 63);
                afh[ct] = *(const bf16x8*)&A[ro];
            }
            int go = it * 64 + k0 + quad * 8;
            bf16x8 b0h = *(const bf16x8*)(w0h + go);
            bf16x8 b1h = *(const bf16x8*)(w1h + go);
#pragma unroll
            for (int ct = 0; ct < 4; ++ct) {
                acc[ct][0] = __builtin_amdgcn_mfma_f32_16x16x32_bf16(afh[ct], b0h, acc[ct][0], 0, 0, 0);
                acc[ct][1] = __builtin_amdgcn_mfma_f32_16x16x32_bf16(afh[ct], b1h, acc[ct][1], 0, 0, 0);
            }
        }
        if (it < 7) {                         // stage prefetched tile into idle buf
            u16* An = Ash[1 - cur];
            *(ushort4*)&An[(cq + 0) * SPAD + colw] = make_ushort4(r0.x, r1.x, r2.x, r3.x);
            *(ushort4*)&An[(cq + 1) * SPAD + colw] = make_ushort4(r0.y, r1.y, r2.y, r3.y);
            *(ushort4*)&An[(cq + 2) * SPAD + colw] = make_ushort4(r0.z, r1.z, r2.z, r3.z);
            *(ushort4*)&An[(cq + 3) * SPAD + colw] = make_ushort4(r0.w, r1.w, r2.w, r3.w);
        }
    }
    float* xb = xh + (size_t)(b << 6) * 128;
#pragma unroll
    for (int ct = 0; ct < 4; ++ct)
#pragma unroll
        for (int lt = 0; lt < 2; ++lt)
#pragma unroll
            for (int r = 0; r < 4; ++r)
                atomicAdd(xb + (size_t)(ct * 16 + quad * 4 + r) * 128 + l0 + lt * 16 + l16,
                          acc[ct][lt][r]);
}

// ---------------------------------------------------------------------------
// hmix via MFMA (unchanged from R11).  grid (32, 16) x 256.
#define XPAD 136
#define TPAD 72
__global__ __launch_bounds__(256) void k_hmix_mfma(
        const float* __restrict__ xh, const u16* __restrict__ Hbf,
        const u16* __restrict__ WsT, float* __restrict__ y, int lay) {
    __shared__ u16 xsb[64 * XPAD];   // [i][l]
    __shared__ u16 Ts[128 * TPAD];   // [k][i]
    int t = threadIdx.x;
    int wave = t >> 6, lane = t & 63, quad = lane >> 4, l16 = lane & 15;
    int b = blockIdx.x, j = blockIdx.y;
    const float* xb = xh + (size_t)b * DIM * MODE;
    for (int idx = t; idx < DIM * MODE; idx += 256)
        xsb[(idx >> 7) * XPAD + (idx & 127)] = to_bf16(xb[idx]);
    __syncthreads();
    int k_base = wave * 32;
    {
        f32x4 acc[2][4] = {};
        const u16* Hj = Hbf + (size_t)j * MODE * MODE;
#pragma unroll
        for (int l0 = 0; l0 < 128; l0 += 32) {
            bf16x8 af[2], bf[4];
#pragma unroll
            for (int mt = 0; mt < 2; ++mt)
                af[mt] = *(const bf16x8*)(Hj + (size_t)(k_base + mt * 16 + l16) * 128 + l0 + quad * 8);
#pragma unroll
            for (int nt = 0; nt < 4; ++nt)
                bf[nt] = *(const bf16x8*)&xsb[(nt * 16 + l16) * XPAD + l0 + quad * 8];
#pragma unroll
            for (int mt = 0; mt < 2; ++mt)
#pragma unroll
                for (int nt = 0; nt < 4; ++nt)
                    acc[mt][nt] = __builtin_amdgcn_mfma_f32_16x16x32_bf16(af[mt], bf[nt], acc[mt][nt], 0, 0, 0);
        }
#pragma unroll
        for (int mt = 0; mt < 2; ++mt)
#pragma unroll
            for (int nt = 0; nt < 4; ++nt)
#pragma unroll
                for (int r = 0; r < 4; ++r)
                    Ts[(k_base + mt * 16 + quad * 4 + r) * TPAD + nt * 16 + l16] =
                        to_bf16(acc[mt][nt][r]);
    }
    __syncthreads();
    {
        f32x4 acc[4][2] = {};
        const u16* Wj = WsT + ((size_t)lay * JM + j) * DIM * DIM;
#pragma unroll
        for (int i0 = 0; i0 < 64; i0 += 32) {
            bf16x8 af[4], bf[2];
#pragma unroll
            for (int mt = 0; mt < 4; ++mt)
                af[mt] = *(const bf16x8*)(Wj + (size_t)(mt * 16 + l16) * 64 + i0 + quad * 8);
#pragma unroll
            for (int nt = 0; nt < 2; ++nt)
                bf[nt] = *(const bf16x8*)&Ts[(k_base + nt * 16 + l16) * TPAD + i0 + quad * 8];
#pragma unroll
            for (int mt = 0; mt < 4; ++mt)
#pragma unroll
                for (int nt = 0; nt < 2; ++nt)
                    acc[mt][nt] = __builtin_amdgcn_mfma_f32_16x16x32_bf16(af[mt], bf[nt], acc[mt][nt], 0, 0, 0);
        }
        float* yb = y + (size_t)b * DIM * MODE;
#pragma unroll
        for (int mt = 0; mt < 4; ++mt)
#pragma unroll
            for (int nt = 0; nt < 2; ++nt)
#pragma unroll
                for (int r = 0; r < 4; ++r)
                    atomicAdd(yb + (size_t)(mt * 16 + quad * 4 + r) * 128 + k_base + nt * 16 + l16,
                              acc[mt][nt][r]);
    }
}

// A buffer in FRAG-MAJOR layout (y|Wconv, single bf16 plane).  grid (32) x 256
__global__ __launch_bounds__(256) void k_build_A(
        const float* __restrict__ y, const float* __restrict__ Wconv,
        u16* __restrict__ Ah, int lay) {
    int b = blockIdx.x;
    for (int idx = threadIdx.x; idx < 12288; idx += 256) {
        int i = idx & 7, l16 = (idx >> 3) & 15, quad = (idx >> 7) & 3,
            ot = (idx >> 9) & 3, ks = idx >> 11;
        int o = ot * 16 + l16;
        int k = ks * 32 + quad * 8 + i;
        float v = (k < 128) ? y[((size_t)b * DIM + o) * MODE + k]
                            : Wconv[(size_t)lay * DIM * DIM + o * DIM + (k - 128)];
        Ah[(size_t)b * 12288 + idx] = to_bf16(v);
    }
}

// ---------------------------------------------------------------------------
// inv_conv: h' = act(A(64x192) @ B(192 x 128x) + bconv), in-place on h.
// 4 subtiles/block with PING-PONG LDS: subtile s+1's h loads into regs at the
// top of subtile s (overlapping K-loop+epilogue), staged to the idle buffer.
// DO_MLP (compile-time): lay2 computes final MLP from LDS tile, skips
// writeback.  grid (32 b, 32 xt) x 256 (4 waves; wave = 64o x 32x).
#define CPAD 72
template <bool DO_MLP>
__global__ __launch_bounds__(256, 4) void k_inv_conv_mfma(
        const u16* __restrict__ Afh,
        const u16* __restrict__ Bfh,
        u16* __restrict__ Hh,
        const float* __restrict__ bconv, int lay,
        const u16* __restrict__ W1h,
        const float* __restrict__ b1, const float* __restrict__ W2,
        const float* __restrict__ b2, float* __restrict__ out) {
    __shared__ u16 hsh[2][128 * CPAD];
    int t = threadIdx.x;
    int wave = t >> 6, lane = t & 63, quad = lane >> 4, l16 = lane & 15;
    int b = blockIdx.x;
    int xbase = blockIdx.y * 512;
    int xw = wave * 32;
    const u16* afb_h = Afh + (size_t)b * 12288;
    int srow = t >> 3, sc8 = (t & 7) * 8;   // staging map: 4 chunks/thread

    bf16x8 pf[4];
#pragma unroll
    for (int it = 0; it < 4; ++it) {
        int row = srow + it * 32;
        pf[it] = *(const bf16x8*)(Hh + ((size_t)(b << 14) + xbase + row) * 64 + sc8);
    }
#pragma unroll
    for (int it = 0; it < 4; ++it)
        *(bf16x8*)&hsh[0][(srow + it * 32) * CPAD + sc8] = pf[it];

    for (int s = 0; s < 4; ++s) {
        int cur = s & 1;
        __syncthreads();                    // hsh[cur] staged
        if (s < 3) {                        // prefetch subtile s+1 (overlaps all below)
#pragma unroll
            for (int it = 0; it < 4; ++it) {
                int row = srow + it * 32;
                pf[it] = *(const bf16x8*)(Hh + ((size_t)(b << 14) + xbase + (s + 1) * 128 + row) * 64 + sc8);
            }
        }
        int x0 = xbase + s * 128;
        const u16* hs = hsh[cur];
        f32x4 acc[4][2] = {};
#pragma unroll
        for (int ks = 0; ks < 6; ++ks) {
            bf16x8 afh[4], bfh[2];
#pragma unroll
            for (int ot = 0; ot < 4; ++ot) {
                size_t ao = (size_t)(((ks * 4 + ot) * 4 + quad) * 16 + l16) * 8;
                afh[ot] = *(const bf16x8*)(afb_h + ao);
            }
#pragma unroll
            for (int x2 = 0; x2 < 2; ++x2) {
                int xl = xw + x2 * 16 + l16;
                if (ks < 4) {
                    size_t bo = (size_t)((ks * 4 + quad) * 16384 + x0 + xl) * 8;
                    bfh[x2] = *(const bf16x8*)(Bfh + bo);
                } else {
                    int ko = (ks - 4) * 32 + quad * 8;
                    bfh[x2] = *(const bf16x8*)&hs[xl * CPAD + ko];
                }
            }
#pragma unroll
            for (int ot = 0; ot < 4; ++ot)
#pragma unroll
                for (int x2 = 0; x2 < 2; ++x2)
                    acc[ot][x2] = __builtin_amdgcn_mfma_f32_16x16x32_bf16(afh[ot], bfh[x2], acc[ot][x2], 0, 0, 0);
        }
        __syncthreads();                    // all reads of hsh[cur] done

        u16* hw = hsh[cur];
#pragma unroll
        for (int ot = 0; ot < 4; ++ot) {
            float4 bc = *(const float4*)(bconv + lay * DIM + ot * 16 + quad * 4);
#pragma unroll
            for (int x2 = 0; x2 < 2; ++x2) {
                int xl = xw + x2 * 16 + l16;
                float vr[4] = {acc[ot][x2][0] + bc.x, acc[ot][x2][1] + bc.y,
                               acc[ot][x2][2] + bc.z, acc[ot][x2][3] + bc.w};
                if (!DO_MLP) {
#pragma unroll
                    for (int r = 0; r < 4; ++r) vr[r] = gelu_fast(vr[r]);
                }
                ushort4 uh;
                uh.x = to_bf16(vr[0]); uh.y = to_bf16(vr[1]);
                uh.z = to_bf16(vr[2]); uh.w = to_bf16(vr[3]);
                *(ushort4*)&hw[xl * CPAD + ot * 16 + quad * 4] = uh;
            }
        }

        if (!DO_MLP) {
            __syncthreads();                // C-stage complete before streamout
#pragma unroll
            for (int it = 0; it < 4; ++it) {
                int row = srow + it * 32;
                size_t dst = ((size_t)(b << 14) + x0 + row) * 64 + sc8;
                *(bf16x8*)(Hh + dst) = *(const bf16x8*)&hw[row * CPAD + sc8];
            }
        } else {
            // fused final MLP — reads only this wave's own rows (xw..xw+31),
            // written by this wave above: no barrier needed.
#pragma unroll
            for (int x2 = 0; x2 < 2; ++x2) {
                bf16x8 ah[2];
#pragma unroll
                for (int ks = 0; ks < 2; ++ks) {
                    int ro = (xw + x2 * 16 + l16) * CPAD + ks * 32 + quad * 8;
                    ah[ks] = *(const bf16x8*)&hw[ro];
                }
                float vo[4] = {0.f, 0.f, 0.f, 0.f};
#pragma unroll
                for (int ft = 0; ft < 8; ++ft) {
                    f32x4 a2 = {};
#pragma unroll
                    for (int ks = 0; ks < 2; ++ks) {
                        size_t o = (size_t)(ft * 16 + l16) * 64 + ks * 32 + quad * 8;
                        bf16x8 bh = *(const bf16x8*)(W1h + o);
                        a2 = __builtin_amdgcn_mfma_f32_16x16x32_bf16(ah[ks], bh, a2, 0, 0, 0);
                    }
                    float bb = b1[ft * 16 + l16];
                    float w2 = W2[ft * 16 + l16];
#pragma unroll
                    for (int r = 0; r < 4; ++r)
                        vo[r] += gelu_fast(a2[r] + bb) * w2;
                }
#pragma unroll
                for (int r = 0; r < 4; ++r) {
                    float v = vo[r];
                    v += __shfl_xor(v, 1);
                    v += __shfl_xor(v, 2);
                    v += __shfl_xor(v, 4);
                    v += __shfl_xor(v, 8);
                    vo[r] = v;
                }
                if (l16 == 0) {
                    float bb2 = b2[0];
                    float4 o4 = make_float4(vo[0] + bb2, vo[1] + bb2, vo[2] + bb2, vo[3] + bb2);
                    *(float4*)(out + (size_t)b * NXX + x0 + xw + x2 * 16 + quad * 4) = o4;
                }
            }
        }

        if (s < 3) {                        // stage prefetched subtile into idle buf
            u16* hn = hsh[1 - cur];
#pragma unroll
            for (int it = 0; it < 4; ++it)
                *(bf16x8*)&hn[(srow + it * 32) * CPAD + sc8] = pf[it];
        }
    }
}

// ---------------------------------------------------------------------------
extern "C" void kernel_launch(void* const* d_in, const int* in_sizes, int n_in,
                              void* d_out, int out_size, void* d_ws, size_t ws_size,
                              hipStream_t stream) {
    const float* x      = (const float*)d_in[0];
    const float* bases  = (const float*)d_in[1];
    const float* wbases = (const float*)d_in[2];
    const float* product= (const float*)d_in[3];
    const float* Dout   = (const float*)d_in[4];
    const float* Din    = (const float*)d_in[5];
    const float* A      = (const float*)d_in[6];
    const float* Bm     = (const float*)d_in[7];
    const float* Wsp    = (const float*)d_in[8];
    const float* Wconv  = (const float*)d_in[9];
    const float* bconv  = (const float*)d_in[10];
    const float* W0     = (const float*)d_in[11];
    const float* b0     = (const float*)d_in[12];
    const float* W1     = (const float*)d_in[13];
    const float* b1     = (const float*)d_in[14];
    const float* W2     = (const float*)d_in[15];
    const float* b2     = (const float*)d_in[16];
    float* out = (float*)d_out;

    const size_t need = 79314944;
    if (ws_size < need) {
        k_zero<<<dim3((out_size + 255) / 256), dim3(256), 0, stream>>>(out, out_size);
        return;
    }

    char* W = (char*)d_ws;
    size_t off = 0;
    auto alloc = [&](size_t bytes) { void* p = W + off; off += bytes; return p; };
    u16*   Hbf      = (u16*)alloc(524288);
    u16*   WsT      = (u16*)alloc(393216);
    u16*   bases_hi = (u16*)alloc(4194304);
    u16*   wbT_hi   = (u16*)alloc(4194304);
    u16*   Abuf_hi  = (u16*)alloc(786432);
    float* ybuf     = (float*)alloc(1048576);
    float* xh       = (float*)alloc(1048576);   // must follow ybuf (joint zeroing)
    u16*   h_hi     = (u16*)alloc(67108864);
    u16*   w1t_hi   = (u16*)alloc(16384);

    k_build_H<<<dim3(1024), dim3(256), 0, stream>>>(Dout, Din, product, A, Bm, Hbf);
    k_setup_wst<<<dim3(768), dim3(256), 0, stream>>>(Wsp, WsT);
    k_setup_bases<<<dim3(8192), dim3(256), 0, stream>>>(bases, bases_hi);
    k_setup_wbT<<<dim3(512, 4), dim3(256), 0, stream>>>(wbases, wbT_hi);
    k_setup_w1t<<<dim3(32), dim3(256), 0, stream>>>(W1, w1t_hi);
    k_fc0<<<dim3(512, B_SZ), dim3(256), 0, stream>>>(x, W0, b0, h_hi);

    for (int lay = 0; lay < N_LAY; ++lay) {
        int last = (lay == N_LAY - 1);
        k_zero<<<dim3(2048), dim3(256), 0, stream>>>(ybuf, 524288);  // ybuf + xh
        k_spectral_mfma<<<dim3(B_SZ, 32), dim3(256), 0, stream>>>(
            h_hi, wbT_hi, xh);
        k_hmix_mfma<<<dim3(B_SZ, JM), dim3(256), 0, stream>>>(
            xh, Hbf, WsT, ybuf, lay);
        k_build_A<<<dim3(B_SZ), dim3(256), 0, stream>>>(ybuf, Wconv, Abuf_hi, lay);
        dim3 g(B_SZ, 32), blk(256);
        if (last)
            k_inv_conv_mfma<true><<<g, blk, 0, stream>>>(
                Abuf_hi, bases_hi, h_hi, bconv, lay,
                w1t_hi, b1, W2, b2, out);
        else
            k_inv_conv_mfma<false><<<g, blk, 0, stream>>>(
                Abuf_hi, bases_hi, h_hi, bconv, lay,
                w1t_hi, b1, W2, b2, out);
    }
}

// Round 13
// 507.098 us; speedup vs baseline: 1.3711x; 1.3711x over previous
//
#include <hip/hip_runtime.h>
#include <hip/hip_bf16.h>
#include <math.h>

#define B_SZ   32
#define NXX    16384
#define IN_DIM 3
#define DIM    64
#define JM     16
#define MODE   128
#define RANKK  4
#define FC_DIM 128
#define N_LAY  3

typedef __attribute__((ext_vector_type(8))) short bf16x8;
typedef __attribute__((ext_vector_type(4))) float f32x4;
typedef unsigned short u16;

// Fast gelu: v * sigmoid(2u), u = sqrt(2/pi)*(v + 0.044715 v^3).
__device__ __forceinline__ float gelu_fast(float v) {
    float p = v * (0.7978845608f + 0.0356774081f * v * v);
    float e = __expf(-2.f * p);
    return v * __builtin_amdgcn_rcpf(1.f + e);
}
__device__ __forceinline__ u16 to_bf16(float v) {
    __hip_bfloat16 b = __float2bfloat16(v);
    return *(u16*)&b;
}

// ---------------------------------------------------------------------------
__global__ __launch_bounds__(256) void k_zero(float* __restrict__ p, int n) {
    int i = blockIdx.x * 256 + threadIdx.x;
    if (i < n) p[i] = 0.f;
}

// H[j,k,l] bf16 row-major (l contig = A-frag-ready for m=k, kk=l).
__global__ __launch_bounds__(256) void k_build_H(
        const float* __restrict__ Dout, const float* __restrict__ Din,
        const float* __restrict__ product, const float* __restrict__ A,
        const float* __restrict__ Bm, u16* __restrict__ Hbf) {
    int idx = blockIdx.x * 256 + threadIdx.x;
    int j = idx >> 14;
    int k = (idx >> 7) & 127;
    int l = idx & 127;
    float v = Dout[j * MODE + k] * Din[j * MODE + l] * product[k * MODE + l];
#pragma unroll
    for (int r = 0; r < RANKK; ++r)
        v += A[(j * RANKK + r) * MODE + k] * Bm[(j * RANKK + r) * MODE + l];
    Hbf[idx] = to_bf16(v);
}

// WsT[lay][j][o][i] = Wsp[lay][i][o][j] bf16 (i contig).  grid 768 x 256.
__global__ __launch_bounds__(256) void k_setup_wst(
        const float* __restrict__ Wsp, u16* __restrict__ WsT) {
    int idx = blockIdx.x * 256 + threadIdx.x;   // ((lay*16+j)*64+o)*64+i
    int i = idx & 63, o = (idx >> 6) & 63, j = (idx >> 12) & 15, lay = idx >> 16;
    WsT[idx] = to_bf16(Wsp[(((size_t)lay * 64 + i) * 64 + o) * 16 + j]);
}

// bases (fp32 [x][k]) -> FRAG-MAJOR single bf16 plane.  grid 8192 x 256.
__global__ __launch_bounds__(256) void k_setup_bases(
        const float* __restrict__ bases, u16* __restrict__ bh) {
    int idx = blockIdx.x * 256 + threadIdx.x;
    int x = idx >> 7, k = idx & 127;
    size_t off = (size_t)(k >> 3) * 131072 + (size_t)x * 8 + (k & 7);
    bh[off] = to_bf16(bases[idx]);
}

// wbT[l][x] = wbases[x][l], single bf16 plane.  grid (512, 4) x 256, LDS-tiled.
__global__ __launch_bounds__(256) void k_setup_wbT(
        const float* __restrict__ wb, u16* __restrict__ Th) {
    __shared__ float tile[32][33];
    int bx = blockIdx.x, bl = blockIdx.y;
    int t = threadIdx.x;
    int i = t >> 5, jj = t & 31;
#pragma unroll
    for (int r = 0; r < 4; ++r)
        tile[i + r * 8][jj] = wb[(size_t)(bx * 32 + i + r * 8) * MODE + bl * 32 + jj];
    __syncthreads();
#pragma unroll
    for (int r = 0; r < 4; ++r) {
        int l = bl * 32 + i + r * 8;
        int x = bx * 32 + jj;
        Th[(size_t)l * NXX + x] = to_bf16(tile[jj][i + r * 8]);
    }
}

// W1T[f*64+c] = W1[c*128+f] single bf16 plane.  grid 32 x 256
__global__ __launch_bounds__(256) void k_setup_w1t(
        const float* __restrict__ W1, u16* __restrict__ wh) {
    int i = blockIdx.x * 256 + threadIdx.x;
    int f = i >> 6, c = i & 63;
    wh[i] = to_bf16(W1[c * FC_DIM + f]);
}

// fc0: h[b,x,c] (single bf16 plane), coalesced ushort8 stores.
// grid (512, 32) x 256.
__global__ __launch_bounds__(256) void k_fc0(
        const float* __restrict__ x, const float* __restrict__ W0,
        const float* __restrict__ b0, u16* __restrict__ hh) {
    __shared__ float w0s[IN_DIM * DIM + DIM];
    int t = threadIdx.x;
    if (t < IN_DIM * DIM) w0s[t] = W0[t];
    if (t < DIM) w0s[IN_DIM * DIM + t] = b0[t];
    __syncthreads();
    int b = blockIdx.y;
    int xi = blockIdx.x * 32 + (t >> 3);
    int c8 = (t & 7) * 8;
    const float* xp = x + ((size_t)b * NXX + xi) * IN_DIM;
    float x0 = xp[0], x1 = xp[1], x2 = xp[2];
    u16 rh[8];
#pragma unroll
    for (int i = 0; i < 8; ++i) {
        int c = c8 + i;
        float v = x0 * w0s[c] + x1 * w0s[DIM + c] + x2 * w0s[2 * DIM + c]
                + w0s[3 * DIM + c];
        rh[i] = to_bf16(v);
    }
    size_t o = ((size_t)(b << 14) + xi) * 64 + c8;
    *(ushort4*)(hh + o)     = make_ushort4(rh[0], rh[1], rh[2], rh[3]);
    *(ushort4*)(hh + o + 4) = make_ushort4(rh[4], rh[5], rh[6], rh[7]);
}

// ---------------------------------------------------------------------------
// Spectral via MFMA: xh[b][c][l] += sum_x h[b][x][c] * wbases[x][l]
// (R11 version: single-buffer, rotation-swizzled LDS transpose.)
// grid (32 b, 32 ks) x 256 (4 waves; wave = 16c x 32l), 512-x slab per block.
#define SPAD 72
__global__ __launch_bounds__(256) void k_spectral_mfma(
        const u16* __restrict__ Hh,
        const u16* __restrict__ Wh,
        float* __restrict__ xh) {
    __shared__ u16 Ash[64 * SPAD];
    int t = threadIdx.x;
    int wave = t >> 6, lane = t & 63, quad = lane >> 4, l16 = lane & 15;
    int b = blockIdx.x;
    int x0 = blockIdx.y * 512;
    int cq = (t & 15) * 4;
    int xq = (t >> 4) * 4;
    int colw = (xq + ((t & 7) << 3)) & 63;
    const u16* srch = Hh + ((size_t)(b << 14) + x0 + xq) * 64 + cq;
    int l0 = wave * 32;
    const u16* w0h = Wh + (size_t)(l0 + l16) * NXX + x0;
    const u16* w1h = Wh + (size_t)(l0 + 16 + l16) * NXX + x0;
    f32x4 acc[4][2] = {};
    for (int kt = 0; kt < 512; kt += 64) {
        __syncthreads();
        {
            const u16* s = srch + (size_t)kt * 64;
            ushort4 r0 = *(const ushort4*)(s);
            ushort4 r1 = *(const ushort4*)(s + 64);
            ushort4 r2 = *(const ushort4*)(s + 128);
            ushort4 r3 = *(const ushort4*)(s + 192);
            *(ushort4*)&Ash[(cq + 0) * SPAD + colw] = make_ushort4(r0.x, r1.x, r2.x, r3.x);
            *(ushort4*)&Ash[(cq + 1) * SPAD + colw] = make_ushort4(r0.y, r1.y, r2.y, r3.y);
            *(ushort4*)&Ash[(cq + 2) * SPAD + colw] = make_ushort4(r0.z, r1.z, r2.z, r3.z);
            *(ushort4*)&Ash[(cq + 3) * SPAD + colw] = make_ushort4(r0.w, r1.w, r2.w, r3.w);
        }
        __syncthreads();
#pragma unroll
        for (int k0 = 0; k0 < 64; k0 += 32) {
            bf16x8 afh[4];
#pragma unroll
            for (int ct = 0; ct < 4; ++ct) {
                int rr = ct * 16 + l16;
                int ro = rr * SPAD + (((k0 + quad * 8) + (((rr >> 2) & 7) << 3)) & 63);
                afh[ct] = *(const bf16x8*)&Ash[ro];
            }
            int go = kt + k0 + quad * 8;
            bf16x8 b0h = *(const bf16x8*)(w0h + go);
            bf16x8 b1h = *(const bf16x8*)(w1h + go);
#pragma unroll
            for (int ct = 0; ct < 4; ++ct) {
                acc[ct][0] = __builtin_amdgcn_mfma_f32_16x16x32_bf16(afh[ct], b0h, acc[ct][0], 0, 0, 0);
                acc[ct][1] = __builtin_amdgcn_mfma_f32_16x16x32_bf16(afh[ct], b1h, acc[ct][1], 0, 0, 0);
            }
        }
    }
    float* xb = xh + (size_t)(b << 6) * 128;
#pragma unroll
    for (int ct = 0; ct < 4; ++ct)
#pragma unroll
        for (int lt = 0; lt < 2; ++lt)
#pragma unroll
            for (int r = 0; r < 4; ++r)
                atomicAdd(xb + (size_t)(ct * 16 + quad * 4 + r) * 128 + l0 + lt * 16 + l16,
                          acc[ct][lt][r]);
}

// ---------------------------------------------------------------------------
// hmix via MFMA (R11).  grid (32, 16) x 256.
#define XPAD 136
#define TPAD 72
__global__ __launch_bounds__(256) void k_hmix_mfma(
        const float* __restrict__ xh, const u16* __restrict__ Hbf,
        const u16* __restrict__ WsT, float* __restrict__ y, int lay) {
    __shared__ u16 xsb[64 * XPAD];   // [i][l]
    __shared__ u16 Ts[128 * TPAD];   // [k][i]
    int t = threadIdx.x;
    int wave = t >> 6, lane = t & 63, quad = lane >> 4, l16 = lane & 15;
    int b = blockIdx.x, j = blockIdx.y;
    const float* xb = xh + (size_t)b * DIM * MODE;
    for (int idx = t; idx < DIM * MODE; idx += 256)
        xsb[(idx >> 7) * XPAD + (idx & 127)] = to_bf16(xb[idx]);
    __syncthreads();
    int k_base = wave * 32;
    {
        f32x4 acc[2][4] = {};
        const u16* Hj = Hbf + (size_t)j * MODE * MODE;
#pragma unroll
        for (int l0 = 0; l0 < 128; l0 += 32) {
            bf16x8 af[2], bf[4];
#pragma unroll
            for (int mt = 0; mt < 2; ++mt)
                af[mt] = *(const bf16x8*)(Hj + (size_t)(k_base + mt * 16 + l16) * 128 + l0 + quad * 8);
#pragma unroll
            for (int nt = 0; nt < 4; ++nt)
                bf[nt] = *(const bf16x8*)&xsb[(nt * 16 + l16) * XPAD + l0 + quad * 8];
#pragma unroll
            for (int mt = 0; mt < 2; ++mt)
#pragma unroll
                for (int nt = 0; nt < 4; ++nt)
                    acc[mt][nt] = __builtin_amdgcn_mfma_f32_16x16x32_bf16(af[mt], bf[nt], acc[mt][nt], 0, 0, 0);
        }
#pragma unroll
        for (int mt = 0; mt < 2; ++mt)
#pragma unroll
            for (int nt = 0; nt < 4; ++nt)
#pragma unroll
                for (int r = 0; r < 4; ++r)
                    Ts[(k_base + mt * 16 + quad * 4 + r) * TPAD + nt * 16 + l16] =
                        to_bf16(acc[mt][nt][r]);
    }
    __syncthreads();
    {
        f32x4 acc[4][2] = {};
        const u16* Wj = WsT + ((size_t)lay * JM + j) * DIM * DIM;
#pragma unroll
        for (int i0 = 0; i0 < 64; i0 += 32) {
            bf16x8 af[4], bf[2];
#pragma unroll
            for (int mt = 0; mt < 4; ++mt)
                af[mt] = *(const bf16x8*)(Wj + (size_t)(mt * 16 + l16) * 64 + i0 + quad * 8);
#pragma unroll
            for (int nt = 0; nt < 2; ++nt)
                bf[nt] = *(const bf16x8*)&Ts[(k_base + nt * 16 + l16) * TPAD + i0 + quad * 8];
#pragma unroll
            for (int mt = 0; mt < 4; ++mt)
#pragma unroll
                for (int nt = 0; nt < 2; ++nt)
                    acc[mt][nt] = __builtin_amdgcn_mfma_f32_16x16x32_bf16(af[mt], bf[nt], acc[mt][nt], 0, 0, 0);
        }
        float* yb = y + (size_t)b * DIM * MODE;
#pragma unroll
        for (int mt = 0; mt < 4; ++mt)
#pragma unroll
            for (int nt = 0; nt < 2; ++nt)
#pragma unroll
                for (int r = 0; r < 4; ++r)
                    atomicAdd(yb + (size_t)(mt * 16 + quad * 4 + r) * 128 + k_base + nt * 16 + l16,
                              acc[mt][nt][r]);
    }
}

// A buffer in FRAG-MAJOR layout (y|Wconv, single bf16 plane).  grid (32) x 256
__global__ __launch_bounds__(256) void k_build_A(
        const float* __restrict__ y, const float* __restrict__ Wconv,
        u16* __restrict__ Ah, int lay) {
    int b = blockIdx.x;
    for (int idx = threadIdx.x; idx < 12288; idx += 256) {
        int i = idx & 7, l16 = (idx >> 3) & 15, quad = (idx >> 7) & 3,
            ot = (idx >> 9) & 3, ks = idx >> 11;
        int o = ot * 16 + l16;
        int k = ks * 32 + quad * 8 + i;
        float v = (k < 128) ? y[((size_t)b * DIM + o) * MODE + k]
                            : Wconv[(size_t)lay * DIM * DIM + o * DIM + (k - 128)];
        Ah[(size_t)b * 12288 + idx] = to_bf16(v);
    }
}

// ---------------------------------------------------------------------------
// inv_conv (R11 structure): h' = act(A(64x192) @ B(192 x 128x) + bconv),
// in-place on h.  Lean path (lay 0/1): epilogue stores DIRECT to global
// (ushort4 per (ot,x2); 4 consecutive o's per lane) — no C LDS restage, no
// post-K-loop barriers.  DO_MLP (lay 2): keeps LDS restage for the fused MLP.
// grid (32 b, 128 xt) x 256 (4 waves; wave = 64o x 32x).
#define CPAD 72
template <bool DO_MLP>
__global__ __launch_bounds__(256, 4) void k_inv_conv_mfma(
        const u16* __restrict__ Afh,
        const u16* __restrict__ Bfh,
        u16* __restrict__ Hh,
        const float* __restrict__ bconv, int lay,
        const u16* __restrict__ W1h,
        const float* __restrict__ b1, const float* __restrict__ W2,
        const float* __restrict__ b2, float* __restrict__ out) {
    __shared__ u16 hsh[128 * CPAD];
    int t = threadIdx.x;
    int wave = t >> 6, lane = t & 63, quad = lane >> 4, l16 = lane & 15;
    int b = blockIdx.x;
    int x0 = blockIdx.y * 128;
#pragma unroll
    for (int it = 0; it < 4; ++it) {
        int idx = it * 256 + t;
        int row = idx >> 3, c8 = (idx & 7) * 8;
        size_t src = ((size_t)(b << 14) + x0 + row) * 64 + c8;
        *(bf16x8*)&hsh[row * CPAD + c8] = *(const bf16x8*)(Hh + src);
    }
    __syncthreads();

    int xw = wave * 32;
    const u16* afb_h = Afh + (size_t)b * 12288;
    f32x4 acc[4][2] = {};
#pragma unroll
    for (int ks = 0; ks < 6; ++ks) {
        bf16x8 afh[4], bfh[2];
#pragma unroll
        for (int ot = 0; ot < 4; ++ot) {
            size_t ao = (size_t)(((ks * 4 + ot) * 4 + quad) * 16 + l16) * 8;
            afh[ot] = *(const bf16x8*)(afb_h + ao);
        }
#pragma unroll
        for (int x2 = 0; x2 < 2; ++x2) {
            int xl = xw + x2 * 16 + l16;
            if (ks < 4) {
                size_t bo = (size_t)((ks * 4 + quad) * 16384 + x0 + xl) * 8;
                bfh[x2] = *(const bf16x8*)(Bfh + bo);
            } else {
                int ko = (ks - 4) * 32 + quad * 8;
                bfh[x2] = *(const bf16x8*)&hsh[xl * CPAD + ko];
            }
        }
#pragma unroll
        for (int ot = 0; ot < 4; ++ot)
#pragma unroll
            for (int x2 = 0; x2 < 2; ++x2)
                acc[ot][x2] = __builtin_amdgcn_mfma_f32_16x16x32_bf16(afh[ot], bfh[x2], acc[ot][x2], 0, 0, 0);
    }

    if (!DO_MLP) {
        // Direct-store epilogue: each lane writes 4 consecutive o's (8 B) for
        // its x.  In-place safe (block-diagonal in x); no barriers needed.
#pragma unroll
        for (int ot = 0; ot < 4; ++ot) {
            float4 bc = *(const float4*)(bconv + lay * DIM + ot * 16 + quad * 4);
#pragma unroll
            for (int x2 = 0; x2 < 2; ++x2) {
                int xl = xw + x2 * 16 + l16;
                float vr[4] = {acc[ot][x2][0] + bc.x, acc[ot][x2][1] + bc.y,
                               acc[ot][x2][2] + bc.z, acc[ot][x2][3] + bc.w};
#pragma unroll
                for (int r = 0; r < 4; ++r) vr[r] = gelu_fast(vr[r]);
                ushort4 uh;
                uh.x = to_bf16(vr[0]); uh.y = to_bf16(vr[1]);
                uh.z = to_bf16(vr[2]); uh.w = to_bf16(vr[3]);
                *(ushort4*)(Hh + ((size_t)(b << 14) + x0 + xl) * 64 + ot * 16 + quad * 4) = uh;
            }
        }
        return;
    }

    // ---- fused lay-2 path: restage C into LDS, then final MLP ----
    __syncthreads();   // all LDS h reads done -> reuse hsh for C staging
#pragma unroll
    for (int ot = 0; ot < 4; ++ot) {
        float4 bc = *(const float4*)(bconv + lay * DIM + ot * 16 + quad * 4);
#pragma unroll
        for (int x2 = 0; x2 < 2; ++x2) {
            int xl = xw + x2 * 16 + l16;
            float vr[4] = {acc[ot][x2][0] + bc.x, acc[ot][x2][1] + bc.y,
                           acc[ot][x2][2] + bc.z, acc[ot][x2][3] + bc.w};
            ushort4 uh;
            uh.x = to_bf16(vr[0]); uh.y = to_bf16(vr[1]);
            uh.z = to_bf16(vr[2]); uh.w = to_bf16(vr[3]);
            *(ushort4*)&hsh[xl * CPAD + ot * 16 + quad * 4] = uh;
        }
    }
    // MLP reads only this wave's own rows (xw..xw+31): no barrier needed.
#pragma unroll
    for (int x2 = 0; x2 < 2; ++x2) {
        bf16x8 ah[2];
#pragma unroll
        for (int ks = 0; ks < 2; ++ks) {
            int ro = (xw + x2 * 16 + l16) * CPAD + ks * 32 + quad * 8;
            ah[ks] = *(const bf16x8*)&hsh[ro];
        }
        float vo[4] = {0.f, 0.f, 0.f, 0.f};
#pragma unroll
        for (int ft = 0; ft < 8; ++ft) {
            f32x4 a2 = {};
#pragma unroll
            for (int ks = 0; ks < 2; ++ks) {
                size_t o = (size_t)(ft * 16 + l16) * 64 + ks * 32 + quad * 8;
                bf16x8 bh = *(const bf16x8*)(W1h + o);
                a2 = __builtin_amdgcn_mfma_f32_16x16x32_bf16(ah[ks], bh, a2, 0, 0, 0);
            }
            float bb = b1[ft * 16 + l16];
            float w2 = W2[ft * 16 + l16];
#pragma unroll
            for (int r = 0; r < 4; ++r)
                vo[r] += gelu_fast(a2[r] + bb) * w2;
        }
#pragma unroll
        for (int r = 0; r < 4; ++r) {
            float v = vo[r];
            v += __shfl_xor(v, 1);
            v += __shfl_xor(v, 2);
            v += __shfl_xor(v, 4);
            v += __shfl_xor(v, 8);
            vo[r] = v;
        }
        if (l16 == 0) {
            float bb2 = b2[0];
            float4 o4 = make_float4(vo[0] + bb2, vo[1] + bb2, vo[2] + bb2, vo[3] + bb2);
            *(float4*)(out + (size_t)b * NXX + x0 + xw + x2 * 16 + quad * 4) = o4;
        }
    }
}

// ---------------------------------------------------------------------------
extern "C" void kernel_launch(void* const* d_in, const int* in_sizes, int n_in,
                              void* d_out, int out_size, void* d_ws, size_t ws_size,
                              hipStream_t stream) {
    const float* x      = (const float*)d_in[0];
    const float* bases  = (const float*)d_in[1];
    const float* wbases = (const float*)d_in[2];
    const float* product= (const float*)d_in[3];
    const float* Dout   = (const float*)d_in[4];
    const float* Din    = (const float*)d_in[5];
    const float* A      = (const float*)d_in[6];
    const float* Bm     = (const float*)d_in[7];
    const float* Wsp    = (const float*)d_in[8];
    const float* Wconv  = (const float*)d_in[9];
    const float* bconv  = (const float*)d_in[10];
    const float* W0     = (const float*)d_in[11];
    const float* b0     = (const float*)d_in[12];
    const float* W1     = (const float*)d_in[13];
    const float* b1     = (const float*)d_in[14];
    const float* W2     = (const float*)d_in[15];
    const float* b2     = (const float*)d_in[16];
    float* out = (float*)d_out;

    const size_t need = 79314944;
    if (ws_size < need) {
        k_zero<<<dim3((out_size + 255) / 256), dim3(256), 0, stream>>>(out, out_size);
        return;
    }

    char* W = (char*)d_ws;
    size_t off = 0;
    auto alloc = [&](size_t bytes) { void* p = W + off; off += bytes; return p; };
    u16*   Hbf      = (u16*)alloc(524288);
    u16*   WsT      = (u16*)alloc(393216);
    u16*   bases_hi = (u16*)alloc(4194304);
    u16*   wbT_hi   = (u16*)alloc(4194304);
    u16*   Abuf_hi  = (u16*)alloc(786432);
    float* ybuf     = (float*)alloc(1048576);
    float* xh       = (float*)alloc(1048576);   // must follow ybuf (joint zeroing)
    u16*   h_hi     = (u16*)alloc(67108864);
    u16*   w1t_hi   = (u16*)alloc(16384);

    k_build_H<<<dim3(1024), dim3(256), 0, stream>>>(Dout, Din, product, A, Bm, Hbf);
    k_setup_wst<<<dim3(768), dim3(256), 0, stream>>>(Wsp, WsT);
    k_setup_bases<<<dim3(8192), dim3(256), 0, stream>>>(bases, bases_hi);
    k_setup_wbT<<<dim3(512, 4), dim3(256), 0, stream>>>(wbases, wbT_hi);
    k_setup_w1t<<<dim3(32), dim3(256), 0, stream>>>(W1, w1t_hi);
    k_fc0<<<dim3(512, B_SZ), dim3(256), 0, stream>>>(x, W0, b0, h_hi);

    for (int lay = 0; lay < N_LAY; ++lay) {
        int last = (lay == N_LAY - 1);
        k_zero<<<dim3(2048), dim3(256), 0, stream>>>(ybuf, 524288);  // ybuf + xh
        k_spectral_mfma<<<dim3(B_SZ, 32), dim3(256), 0, stream>>>(
            h_hi, wbT_hi, xh);
        k_hmix_mfma<<<dim3(B_SZ, JM), dim3(256), 0, stream>>>(
            xh, Hbf, WsT, ybuf, lay);
        k_build_A<<<dim3(B_SZ), dim3(256), 0, stream>>>(ybuf, Wconv, Abuf_hi, lay);
        dim3 g(B_SZ, 128), blk(256);
        if (last)
            k_inv_conv_mfma<true><<<g, blk, 0, stream>>>(
                Abuf_hi, bases_hi, h_hi, bconv, lay,
                w1t_hi, b1, W2, b2, out);
        else
            k_inv_conv_mfma<false><<<g, blk, 0, stream>>>(
                Abuf_hi, bases_hi, h_hi, bconv, lay,
                w1t_hi, b1, W2, b2, out);
    }
}